// Round 13
// baseline (136.448 us; speedup 1.0000x reference)
//
#include <hip/hip_runtime.h>
#include <stdint.h>

#define BATCH 16384
#define NF 768
#define FT 1024
#define RBB 32              // batch rows per block
#define GR 64               // GEMM rows (stm 0-31, nstm 32-63)
#define THREADS 512
#define NKS 12              // 768/64 K-steps
#define CH_COLS 512
#define NWG 1024            // (BATCH/RBB) * 2 col-halves
#define ABYTES (NKS * 4 * 64 * 16)   // 49152 frag-ordered A

typedef int i32x4 __attribute__((ext_vector_type(4)));

// ---- prep: W_ft [FT][NF] f32 -> Wq [FT][NF] i8 (per-row scale 127/absmax) --
__global__ __launch_bounds__(192) void prep_wq(const float* __restrict__ W_ft,
                                               char* __restrict__ Wq,
                                               float* __restrict__ invs) {
    const int o = blockIdx.x;
    const int t = threadIdx.x;
    __shared__ float smax[3];
    __shared__ float sscale;
    const float4 v = *(const float4*)(W_ft + (size_t)o * NF + t * 4);
    float m = fmaxf(fmaxf(fabsf(v.x), fabsf(v.y)), fmaxf(fabsf(v.z), fabsf(v.w)));
    #pragma unroll
    for (int s = 32; s > 0; s >>= 1) m = fmaxf(m, __shfl_down(m, s, 64));
    if ((t & 63) == 0) smax[t >> 6] = m;
    __syncthreads();
    if (t == 0) {
        const float am = fmaxf(fmaxf(smax[0], smax[1]), smax[2]);
        sscale = 127.0f / am;
        invs[o] = am / 127.0f;
    }
    __syncthreads();
    const float s = sscale;
    const float arr[4] = {v.x, v.y, v.z, v.w};
    uint32_t pk = 0;
    #pragma unroll
    for (int j = 0; j < 4; ++j) {
        const int q = (int)rintf(arr[j] * s);
        pk |= ((uint32_t)(unsigned char)(char)q) << (8 * j);
    }
    *(uint32_t*)(Wq + (size_t)o * NF + t * 4) = pk;
}

__device__ __forceinline__ uint32_t pack01(float4 v) {
    return (uint32_t)(v.x != 0.0f) | ((uint32_t)(v.y != 0.0f) << 8)
         | ((uint32_t)(v.z != 0.0f) << 16) | ((uint32_t)(v.w != 0.0f) << 24);
}

// ---- main GEMM, MODE-ablated: 0=stage-only, 1=kloop-only, 2=full -----------
// 8 waves; wave w owns cols [ch*512 + 64w, +64); acc[4][4]; 50 KB LDS;
// __launch_bounds__(512,4) caps 128 regs -> 2 blocks/CU co-resident.
template <int MODE>
__global__ __launch_bounds__(THREADS, 4) void nnue_mfma(
    const float* __restrict__ bstm, const float* __restrict__ bnstm,
    const char* __restrict__ Wq, const float* __restrict__ invs,
    const float* __restrict__ b_ft, const float* __restrict__ W_out,
    float* __restrict__ pbuf, float* __restrict__ dump)
{
    __shared__ __align__(16) char Albs[ABYTES];   // 48 KB
    __shared__ float red[GR][8];                  // 2 KB

    const int t = threadIdx.x;
    const int w = t >> 6;
    const int l = t & 63;
    const int cl = l & 15;
    const int q = l >> 4;
    // XCD-chunked swizzle (NWG%8==0): both col-halves of a row-group share an XCD
    const int bid = (blockIdx.x & 7) * (NWG / 8) + (blockIdx.x >> 3);
    const int rg = bid >> 1;
    const int ch = bid & 1;
    const int b0 = rg * RBB;

    if (MODE != 1) {
        // stage 64 board rows f32 -> i8 {0,1} frag-order LDS.
        // 3072 16B-chunks, 6/thread, 2 batches of 3 (12 float4 in flight).
        #pragma unroll
        for (int bt = 0; bt < 2; ++bt) {
            float4 v[12];
            int row[3], c16[3];
            #pragma unroll
            for (int j = 0; j < 3; ++j) {
                const int id = (bt * 3 + j) * THREADS + t;
                row[j] = id / 48; c16[j] = id - row[j] * 48;
                const float* src = ((row[j] < RBB)
                    ? (bstm + (size_t)(b0 + row[j]) * NF)
                    : (bnstm + (size_t)(b0 + row[j] - RBB) * NF)) + c16[j] * 16;
                #pragma unroll
                for (int k = 0; k < 4; ++k)
                    v[j * 4 + k] = *(const float4*)(src + k * 4);
            }
            __builtin_amdgcn_sched_barrier(0);
            #pragma unroll
            for (int j = 0; j < 3; ++j) {
                uint4 o;
                o.x = pack01(v[j * 4 + 0]); o.y = pack01(v[j * 4 + 1]);
                o.z = pack01(v[j * 4 + 2]); o.w = pack01(v[j * 4 + 3]);
                const int ks = c16[j] >> 2, qq = c16[j] & 3;
                const int rr = row[j] >> 4, c2 = row[j] & 15;
                const int slotA = ((ks * 4 + rr) << 6) + (qq << 4) + c2;
                *(uint4*)(&Albs[(size_t)slotA << 4]) = o;
            }
        }
    }
    __syncthreads();

    if (MODE == 0) {
        // consume staged LDS so nothing is DCE'd; write one float per wave.
        uint32_t s = 0;
        #pragma unroll
        for (int j = 0; j < 6; ++j) {
            const uint4 u = ((const uint4*)Albs)[j * THREADS + t];
            s += u.x + u.y + u.z + u.w;
        }
        float v = (float)s;
        #pragma unroll
        for (int sh = 32; sh > 0; sh >>= 1) v += __shfl_down(v, sh, 64);
        if (l == 0) dump[blockIdx.x * 8 + w] = v;
        return;
    }

    // K-loop: single-buffer B (4x dwordx4 from L2), barrier-free; TLP hides.
    const char* bp = Wq + (size_t)(ch * CH_COLS + w * 64 + cl) * NF + q * 16;
    const i32x4* af = (const i32x4*)Albs;
    i32x4 acc[4][4] = {};
    #pragma unroll
    for (int ks = 0; ks < NKS; ++ks) {
        i32x4 b[4];
        #pragma unroll
        for (int c = 0; c < 4; ++c)
            b[c] = *(const i32x4*)(bp + (size_t)c * 16 * NF + ks * 64);
        i32x4 a[4];
        #pragma unroll
        for (int r = 0; r < 4; ++r)
            a[r] = af[(ks * 4 + r) * 64 + l];
        __builtin_amdgcn_s_setprio(1);
        #pragma unroll
        for (int r = 0; r < 4; ++r)
            #pragma unroll
            for (int c = 0; c < 4; ++c)
                acc[r][c] = __builtin_amdgcn_mfma_i32_16x16x64_i8(
                    a[r], b[c], acc[r][c], 0, 0, 0);
        __builtin_amdgcn_s_setprio(0);
    }

    // epilogue: dequant + bias + SCReLU + partial W_out dot.
    // C/D lane mapping: col=l&15, row=(l>>4)*4+j (validated r5-r12).
    float ps[4][4] = {};
    #pragma unroll
    for (int cc = 0; cc < 4; ++cc) {
        const int col = ch * CH_COLS + w * 64 + cc * 16 + cl;
        const float iv = invs[col];
        const float bf = b_ft[col];
        const float wo0 = W_out[col];
        const float wo1 = W_out[FT + col];
        #pragma unroll
        for (int r = 0; r < 4; ++r) {
            const float wo = (r < 2) ? wo0 : wo1;   // 0-31 stm, 32-63 nstm
            #pragma unroll
            for (int j = 0; j < 4; ++j) {
                float hh = fmaf((float)acc[r][cc][j], iv, bf);
                hh = fminf(fmaxf(hh, 0.0f), 1.0f);
                ps[r][j] = fmaf(hh * hh, wo, ps[r][j]);
            }
        }
    }
    #pragma unroll
    for (int r = 0; r < 4; ++r)
        #pragma unroll
        for (int j = 0; j < 4; ++j) {
            float v = ps[r][j];
            v += __shfl_xor(v, 1, 64);
            v += __shfl_xor(v, 2, 64);
            v += __shfl_xor(v, 4, 64);
            v += __shfl_xor(v, 8, 64);
            if (cl == 0) red[16 * r + 4 * q + j][w] = v;
        }
    __syncthreads();

    if (t < RBB) {
        float x = 0.0f;
        #pragma unroll
        for (int w2 = 0; w2 < 8; ++w2)
            x += red[t][w2] + red[RBB + t][w2];
        if (MODE == 1) dump[NWG * 8 + blockIdx.x * RBB + t] = x;
        else           pbuf[(size_t)ch * BATCH + b0 + t] = x;
    }
}

// ---- finalize: sum col-half partials + bias -> sigmoid ---------------------
__global__ __launch_bounds__(256) void finalize(const float* __restrict__ pbuf,
                                                const float* __restrict__ b_out,
                                                float* __restrict__ out) {
    const int i = blockIdx.x * 256 + threadIdx.x;
    const float x = pbuf[i] + pbuf[BATCH + i] + b_out[0];
    out[i] = 1.0f / (1.0f + expf(-x));
}

extern "C" void kernel_launch(void* const* d_in, const int* in_sizes, int n_in,
                              void* d_out, int out_size, void* d_ws, size_t ws_size,
                              hipStream_t stream) {
    const float* board_stm  = (const float*)d_in[0];
    const float* board_nstm = (const float*)d_in[1];
    const float* W_ft       = (const float*)d_in[2];
    const float* b_ft       = (const float*)d_in[3];
    const float* W_out      = (const float*)d_in[4];
    const float* b_out      = (const float*)d_in[5];
    float* out = (float*)d_out;

    char* Wq = (char*)d_ws;                                   // 768 KB
    float* invs = (float*)((char*)d_ws + (size_t)FT * NF);    // 4 KB
    float* pbuf = (float*)((char*)d_ws + (size_t)FT * NF + 4096);      // 128 KB
    float* dump = (float*)((char*)d_ws + (size_t)FT * NF + 4096 + 131072); // scratch

    prep_wq<<<FT, 192, 0, stream>>>(W_ft, Wq, invs);
    // ablation dispatches (write to scratch; timing read from rocprof)
    nnue_mfma<0><<<NWG, THREADS, 0, stream>>>(board_stm, board_nstm, Wq, invs,
                                              b_ft, W_out, pbuf, dump);
    nnue_mfma<1><<<NWG, THREADS, 0, stream>>>(board_stm, board_nstm, Wq, invs,
                                              b_ft, W_out, pbuf, dump);
    // the real pipeline
    nnue_mfma<2><<<NWG, THREADS, 0, stream>>>(board_stm, board_nstm, Wq, invs,
                                              b_ft, W_out, pbuf, dump);
    finalize<<<BATCH / 256, 256, 0, stream>>>(pbuf, b_out, out);
}

// Round 14
// 83.074 us; speedup vs baseline: 1.6425x; 1.6425x over previous
//
#include <hip/hip_runtime.h>
#include <stdint.h>

#define BATCH 16384
#define NF 768
#define FT 1024
#define RBB 32              // batch rows per tile
#define GR 64               // GEMM rows (stm 0-31, nstm 32-63)
#define THREADS 512
#define NKS 12              // 768/64 K-steps
#define CH_COLS 512
#define NWG 1024            // (BATCH/RBB) * 2 col-halves
#define NRG (BATCH / RBB)   // 512 row-groups
#define ABYTES (NKS * 4 * 64 * 16)   // 49152 frag-ordered A per row-group

typedef int i32x4 __attribute__((ext_vector_type(4)));

// ---- prep: W_ft [FT][NF] f32 -> Wq [FT][NF] i8 (per-row scale 127/absmax) --
__global__ __launch_bounds__(192) void prep_wq(const float* __restrict__ W_ft,
                                               char* __restrict__ Wq,
                                               float* __restrict__ invs) {
    const int o = blockIdx.x;
    const int t = threadIdx.x;
    __shared__ float smax[3];
    __shared__ float sscale;
    const float4 v = *(const float4*)(W_ft + (size_t)o * NF + t * 4);
    float m = fmaxf(fmaxf(fabsf(v.x), fabsf(v.y)), fmaxf(fabsf(v.z), fabsf(v.w)));
    #pragma unroll
    for (int s = 32; s > 0; s >>= 1) m = fmaxf(m, __shfl_down(m, s, 64));
    if ((t & 63) == 0) smax[t >> 6] = m;
    __syncthreads();
    if (t == 0) {
        const float am = fmaxf(fmaxf(smax[0], smax[1]), smax[2]);
        sscale = 127.0f / am;
        invs[o] = am / 127.0f;
    }
    __syncthreads();
    const float s = sscale;
    const float arr[4] = {v.x, v.y, v.z, v.w};
    uint32_t pk = 0;
    #pragma unroll
    for (int j = 0; j < 4; ++j) {
        const int q = (int)rintf(arr[j] * s);
        pk |= ((uint32_t)(unsigned char)(char)q) << (8 * j);
    }
    *(uint32_t*)(Wq + (size_t)o * NF + t * 4) = pk;
}

__device__ __forceinline__ uint32_t pack01(float4 v) {
    return (uint32_t)(v.x != 0.0f) | ((uint32_t)(v.y != 0.0f) << 8)
         | ((uint32_t)(v.z != 0.0f) << 16) | ((uint32_t)(v.w != 0.0f) << 24);
}

__device__ __forceinline__ void gload16(const void* g, void* l) {
    __builtin_amdgcn_global_load_lds(
        (const __attribute__((address_space(1))) unsigned int*)g,
        (__attribute__((address_space(3))) unsigned int*)l, 16, 0, 0);
}

// ---- conv: boards f32 -> i8 {0,1} in frag-order global a8f -----------------
// a8f[rg][slot*16]; slot = ((ks*4+r)*64 + q*16 + cl). Streaming reads,
// scattered-but-L2-local 16B writes. Measured-fast pattern (r8/r9 ~5 TB/s).
__global__ __launch_bounds__(256) void conv_boards(const float* __restrict__ bstm,
                                                   const float* __restrict__ bnstm,
                                                   unsigned char* __restrict__ a8f) {
    const int NCH = BATCH * 48;   // 64B-f32 chunks per board
    for (int g = blockIdx.x * 256 + threadIdx.x; g < 2 * NCH; g += gridDim.x * 256) {
        const int p = (g >= NCH);
        const int gg = p ? g - NCH : g;
        const int brow = gg / 48;
        const int c16 = gg - brow * 48;
        const float4* s = (const float4*)((p ? bnstm : bstm)
                                          + (size_t)brow * NF + c16 * 16);
        uint4 o;
        o.x = pack01(s[0]); o.y = pack01(s[1]);
        o.z = pack01(s[2]); o.w = pack01(s[3]);
        const int rg = brow >> 5;
        const int row = (p << 5) | (brow & 31);     // GEMM row in tile
        const int r = row >> 4, cl = row & 15;
        const int ks = c16 >> 2, q = c16 & 3;
        const int slot = ((ks * 4 + r) << 6) + (q << 4) + cl;
        *(uint4*)(a8f + (size_t)rg * ABYTES + ((size_t)slot << 4)) = o;
    }
}

// ---- fused dense i8-MFMA FT + SCReLU + partial output dot ------------------
// 8 waves; wave w owns cols [ch*512 + 64w, +64); acc[4][4]; 50 KB LDS;
// launch_bounds(512,4) -> 2 blocks/CU. A staged via async global_load_lds
// (lane-linear, no VGPR round-trip, no LDS write conflicts).
__global__ __launch_bounds__(THREADS, 4) void nnue_mfma(
    const unsigned char* __restrict__ a8f,
    const char* __restrict__ Wq, const float* __restrict__ invs,
    const float* __restrict__ b_ft, const float* __restrict__ W_out,
    float* __restrict__ pbuf)
{
    __shared__ __align__(16) char Albs[ABYTES];   // 48 KB
    __shared__ float red[GR][8];                  // 2 KB

    const int t = threadIdx.x;
    const int w = t >> 6;
    const int l = t & 63;
    const int cl = l & 15;
    const int q = l >> 4;
    // XCD-chunked swizzle (NWG % 8 == 0 -> bijective)
    const int bid = (blockIdx.x & 7) * (NWG / 8) + (blockIdx.x >> 3);
    const int rg = bid >> 1;
    const int ch = bid & 1;

    // Phase 1: async A-stage, 6 wave-issues x 64 lanes x 16 B = 48 KB.
    const unsigned char* asrc = a8f + (size_t)rg * ABYTES;
    #pragma unroll
    for (int j = 0; j < 6; ++j) {
        const int chunk = ((j * 8 + w) * 64 + l);
        gload16(asrc + ((size_t)chunk << 4), Albs + ((size_t)chunk << 4));
    }
    __syncthreads();   // drains vmcnt + lgkm; A tile ready

    // Phase 2: K-loop, single-buffer B from L2, barrier-free.
    const char* bp = Wq + (size_t)(ch * CH_COLS + w * 64 + cl) * NF + q * 16;
    const i32x4* af = (const i32x4*)Albs;
    i32x4 acc[4][4] = {};
    #pragma unroll
    for (int ks = 0; ks < NKS; ++ks) {
        i32x4 b[4];
        #pragma unroll
        for (int c = 0; c < 4; ++c)
            b[c] = *(const i32x4*)(bp + (size_t)c * 16 * NF + ks * 64);
        i32x4 a[4];
        #pragma unroll
        for (int r = 0; r < 4; ++r)
            a[r] = af[(ks * 4 + r) * 64 + l];
        __builtin_amdgcn_s_setprio(1);
        #pragma unroll
        for (int r = 0; r < 4; ++r)
            #pragma unroll
            for (int c = 0; c < 4; ++c)
                acc[r][c] = __builtin_amdgcn_mfma_i32_16x16x64_i8(
                    a[r], b[c], acc[r][c], 0, 0, 0);
        __builtin_amdgcn_s_setprio(0);
    }

    // Phase 3: dequant + bias + SCReLU + partial W_out dot.
    // C/D lane mapping: col=l&15, row=(l>>4)*4+j (validated r5-r13).
    float ps[4][4] = {};
    #pragma unroll
    for (int cc = 0; cc < 4; ++cc) {
        const int col = ch * CH_COLS + w * 64 + cc * 16 + cl;
        const float iv = invs[col];
        const float bf = b_ft[col];
        const float wo0 = W_out[col];
        const float wo1 = W_out[FT + col];
        #pragma unroll
        for (int r = 0; r < 4; ++r) {
            const float wo = (r < 2) ? wo0 : wo1;   // 0-31 stm, 32-63 nstm
            #pragma unroll
            for (int j = 0; j < 4; ++j) {
                float hh = fmaf((float)acc[r][cc][j], iv, bf);
                hh = fminf(fmaxf(hh, 0.0f), 1.0f);
                ps[r][j] = fmaf(hh * hh, wo, ps[r][j]);
            }
        }
    }
    #pragma unroll
    for (int r = 0; r < 4; ++r)
        #pragma unroll
        for (int j = 0; j < 4; ++j) {
            float v = ps[r][j];
            v += __shfl_xor(v, 1, 64);
            v += __shfl_xor(v, 2, 64);
            v += __shfl_xor(v, 4, 64);
            v += __shfl_xor(v, 8, 64);
            if (cl == 0) red[16 * r + 4 * q + j][w] = v;
        }
    __syncthreads();

    if (t < RBB) {
        float x = 0.0f;
        #pragma unroll
        for (int w2 = 0; w2 < 8; ++w2)
            x += red[t][w2] + red[RBB + t][w2];
        pbuf[(size_t)ch * BATCH + rg * RBB + t] = x;
    }
}

// ---- fallback GEMM (small ws): r13 MODE2 path, f32 boards staged in-kernel -
__global__ __launch_bounds__(THREADS, 4) void nnue_mfma_fb(
    const float* __restrict__ bstm, const float* __restrict__ bnstm,
    const char* __restrict__ Wq, const float* __restrict__ invs,
    const float* __restrict__ b_ft, const float* __restrict__ W_out,
    float* __restrict__ pbuf)
{
    __shared__ __align__(16) char Albs[ABYTES];
    __shared__ float red[GR][8];
    const int t = threadIdx.x;
    const int w = t >> 6;
    const int l = t & 63;
    const int cl = l & 15;
    const int q = l >> 4;
    const int bid = (blockIdx.x & 7) * (NWG / 8) + (blockIdx.x >> 3);
    const int rg = bid >> 1;
    const int ch = bid & 1;
    const int b0 = rg * RBB;

    #pragma unroll
    for (int bt = 0; bt < 2; ++bt) {
        float4 v[12];
        int row[3], c16[3];
        #pragma unroll
        for (int j = 0; j < 3; ++j) {
            const int id = (bt * 3 + j) * THREADS + t;
            row[j] = id / 48; c16[j] = id - row[j] * 48;
            const float* src = ((row[j] < RBB)
                ? (bstm + (size_t)(b0 + row[j]) * NF)
                : (bnstm + (size_t)(b0 + row[j] - RBB) * NF)) + c16[j] * 16;
            #pragma unroll
            for (int k = 0; k < 4; ++k)
                v[j * 4 + k] = *(const float4*)(src + k * 4);
        }
        __builtin_amdgcn_sched_barrier(0);
        #pragma unroll
        for (int j = 0; j < 3; ++j) {
            uint4 o;
            o.x = pack01(v[j * 4 + 0]); o.y = pack01(v[j * 4 + 1]);
            o.z = pack01(v[j * 4 + 2]); o.w = pack01(v[j * 4 + 3]);
            const int ks = c16[j] >> 2, qq = c16[j] & 3;
            const int rr = row[j] >> 4, c2 = row[j] & 15;
            *(uint4*)(&Albs[(size_t)(((ks * 4 + rr) << 6) + (qq << 4) + c2) << 4]) = o;
        }
    }
    __syncthreads();

    const char* bp = Wq + (size_t)(ch * CH_COLS + w * 64 + cl) * NF + q * 16;
    const i32x4* af = (const i32x4*)Albs;
    i32x4 acc[4][4] = {};
    #pragma unroll
    for (int ks = 0; ks < NKS; ++ks) {
        i32x4 b[4];
        #pragma unroll
        for (int c = 0; c < 4; ++c)
            b[c] = *(const i32x4*)(bp + (size_t)c * 16 * NF + ks * 64);
        i32x4 a[4];
        #pragma unroll
        for (int r = 0; r < 4; ++r)
            a[r] = af[(ks * 4 + r) * 64 + l];
        #pragma unroll
        for (int r = 0; r < 4; ++r)
            #pragma unroll
            for (int c = 0; c < 4; ++c)
                acc[r][c] = __builtin_amdgcn_mfma_i32_16x16x64_i8(
                    a[r], b[c], acc[r][c], 0, 0, 0);
    }
    float ps[4][4] = {};
    #pragma unroll
    for (int cc = 0; cc < 4; ++cc) {
        const int col = ch * CH_COLS + w * 64 + cc * 16 + cl;
        const float iv = invs[col];
        const float bf = b_ft[col];
        const float wo0 = W_out[col];
        const float wo1 = W_out[FT + col];
        #pragma unroll
        for (int r = 0; r < 4; ++r) {
            const float wo = (r < 2) ? wo0 : wo1;
            #pragma unroll
            for (int j = 0; j < 4; ++j) {
                float hh = fmaf((float)acc[r][cc][j], iv, bf);
                hh = fminf(fmaxf(hh, 0.0f), 1.0f);
                ps[r][j] = fmaf(hh * hh, wo, ps[r][j]);
            }
        }
    }
    #pragma unroll
    for (int r = 0; r < 4; ++r)
        #pragma unroll
        for (int j = 0; j < 4; ++j) {
            float v = ps[r][j];
            v += __shfl_xor(v, 1, 64);
            v += __shfl_xor(v, 2, 64);
            v += __shfl_xor(v, 4, 64);
            v += __shfl_xor(v, 8, 64);
            if (cl == 0) red[16 * r + 4 * q + j][w] = v;
        }
    __syncthreads();
    if (t < RBB) {
        float x = 0.0f;
        #pragma unroll
        for (int w2 = 0; w2 < 8; ++w2)
            x += red[t][w2] + red[RBB + t][w2];
        pbuf[(size_t)ch * BATCH + rg * RBB + t] = x;
    }
}

// ---- finalize: sum col-half partials + bias -> sigmoid ---------------------
__global__ __launch_bounds__(256) void finalize(const float* __restrict__ pbuf,
                                                const float* __restrict__ b_out,
                                                float* __restrict__ out) {
    const int i = blockIdx.x * 256 + threadIdx.x;
    const float x = pbuf[i] + pbuf[BATCH + i] + b_out[0];
    out[i] = 1.0f / (1.0f + expf(-x));
}

extern "C" void kernel_launch(void* const* d_in, const int* in_sizes, int n_in,
                              void* d_out, int out_size, void* d_ws, size_t ws_size,
                              hipStream_t stream) {
    const float* board_stm  = (const float*)d_in[0];
    const float* board_nstm = (const float*)d_in[1];
    const float* W_ft       = (const float*)d_in[2];
    const float* b_ft       = (const float*)d_in[3];
    const float* W_out      = (const float*)d_in[4];
    const float* b_out      = (const float*)d_in[5];
    float* out = (float*)d_out;

    char* Wq = (char*)d_ws;                                        // 768 KB
    float* invs = (float*)((char*)d_ws + (size_t)FT * NF);         // 4 KB
    float* pbuf = (float*)((char*)d_ws + (size_t)FT * NF + 4096);  // 128 KB
    unsigned char* a8f = (unsigned char*)d_ws + (size_t)FT * NF + 4096 + 131072;
    const size_t needed = (size_t)FT * NF + 4096 + 131072 + (size_t)NRG * ABYTES;

    prep_wq<<<FT, 192, 0, stream>>>(W_ft, Wq, invs);
    if (ws_size >= needed) {
        conv_boards<<<2048, 256, 0, stream>>>(board_stm, board_nstm, a8f);
        nnue_mfma<<<NWG, THREADS, 0, stream>>>(a8f, Wq, invs, b_ft, W_out, pbuf);
    } else {
        nnue_mfma_fb<<<NWG, THREADS, 0, stream>>>(board_stm, board_nstm, Wq,
                                                  invs, b_ft, W_out, pbuf);
    }
    finalize<<<BATCH / 256, 256, 0, stream>>>(pbuf, b_out, out);
}